// Round 1
// baseline (145.259 us; speedup 1.0000x reference)
//
#include <hip/hip_runtime.h>

// Problem constants
#define NROWS 512          // N
#define FEAT  8192         // NUM_CHANNELS*4*4
#define BDIM  64
#define CDIM  16
#define MCOLS 1024         // BDIM*CDIM
#define OUTC  8256         // FEAT + BDIM
#define KSPLIT 8
#define KCHUNK (FEAT / KSPLIT)     // 1024
#define KSTEPS (KCHUNK / 64)       // 16
#define MSIZE  (NROWS * MCOLS)     // 524288 floats = 2 MB

typedef __bf16 bf16x8 __attribute__((ext_vector_type(8)));
typedef float  floatx4 __attribute__((ext_vector_type(4)));

// two fp32 -> packed bf16 pair (HW RNE via v_cvt; compiler fuses to cvt_pk)
static __device__ __forceinline__ unsigned int pk2(float a, float b) {
    unsigned short lo = __builtin_bit_cast(unsigned short, (__bf16)a);
    unsigned short hi = __builtin_bit_cast(unsigned short, (__bf16)b);
    return (unsigned int)lo | ((unsigned int)hi << 16);
}

// ---------------------------------------------------------------------------
// k_gemm: M = x@T, fused fp32->bf16 conversion + T transpose in staging.
// 128x128 tile, 512 thr (8 waves 2x4), BK=64, split-K=8, grid 256 = 1 blk/CU.
// XCD swizzle: ks == XCD id, so each XCD's L2 sees one k-chunk of x and T.
// LDS rows are 64 k = 128 B = 8 chunks of 16 B; chunk c of row r stored at
// phys chunk c ^ s(r), s(r) = (r&7)^((r>>2)&7).  This is minimum-cycle on:
//   A write (4 rows x 16 k-quads/instr), B write (32 n-rows stride 4, fixed
//   j/instr: s takes 8 distinct values over n4&7), frag read (16 rows x 4 fq).
// Pipeline per K-step: [cvt+ds_write k] barrier [issue loads k+1][MFMA k]
// barrier -- next loads are in flight across the whole MFMA phase.
// ---------------------------------------------------------------------------
__global__ __launch_bounds__(512, 2) void k_gemm(const float* __restrict__ x,
                                                 const float* __restrict__ T,
                                                 float* __restrict__ Mp) {
    __shared__ __align__(16) unsigned short ldsA[128 * 64];   // 16 KB
    __shared__ __align__(16) unsigned short ldsB[128 * 64];   // 16 KB
    char* ldsAc = (char*)ldsA;
    char* ldsBc = (char*)ldsB;

    int bid = blockIdx.x;
    int wg = (bid & 7) * 32 + (bid >> 3);        // XCD-contiguous remap
    int mt = wg & 3, nt = (wg >> 2) & 7, ks = wg >> 5;
    int m0 = mt * 128, n0 = nt * 128, kbase = ks * KCHUNK;
    int t = threadIdx.x, w = t >> 6, l = t & 63;

    // ---- staging geometry: A rows (k-contiguous, no transpose)
    int arow = t >> 4, aq = t & 15;              // 32 rows (+r*32), 16 k-quads
    const float* gA = x + (size_t)(m0 + arow) * FEAT + kbase + aq * 4;
    int swa = (arow & 7) ^ ((arow >> 2) & 7);    // invariant under +32 rows
    int wA = arow * 128 + (((aq >> 1) ^ swa) << 4) + ((aq & 1) << 3);

    // ---- staging geometry: B (transpose T[k][n] -> n-major rows)
    int n4 = t & 31, kg = t >> 5;                // 32 n-quads, 16 k-quads
    const float* gB = T + (size_t)(kbase + kg * 4) * MCOLS + n0 + n4 * 4;
    int wB[4];
#pragma unroll
    for (int j = 0; j < 4; ++j) {
        int n = n4 * 4 + j;
        int swn = (n & 7) ^ ((n >> 2) & 7);
        wB[j] = n * 128 + (((kg >> 1) ^ swn) << 4) + ((kg & 1) << 3);
    }

    // ---- compute geometry: wave (wr=w>>2, wc=w&3) owns 64x32 of C
    int wr = w >> 2, wc = w & 3, fm = l & 15, fq = l >> 4;
    int swf = (fm & 7) ^ ((fm >> 2) & 7);
    int baseA = (wr * 64 + fm) * 128 + ((fq ^ swf) << 4);
    int baseB = (wc * 32 + fm) * 128 + ((fq ^ swf) << 4);
    // rows +16 flip bit2 of s(row): handled by ^((a&1)<<6) / ^((b&1)<<6)

    float4 va[4], vb[4];
    auto issue = [&](int KK) {
        int kko = KK * 64;
        va[0] = *(const float4*)(gA + kko);
        va[1] = *(const float4*)(gA + 32 * FEAT + kko);
        va[2] = *(const float4*)(gA + 64 * FEAT + kko);
        va[3] = *(const float4*)(gA + 96 * FEAT + kko);
        vb[0] = *(const float4*)(gB + (size_t)(kko + 0) * MCOLS);
        vb[1] = *(const float4*)(gB + (size_t)(kko + 1) * MCOLS);
        vb[2] = *(const float4*)(gB + (size_t)(kko + 2) * MCOLS);
        vb[3] = *(const float4*)(gB + (size_t)(kko + 3) * MCOLS);
    };

    issue(0);
    floatx4 acc[4][2] = {};

    for (int kk = 0; kk < KSTEPS; ++kk) {
        // convert + LDS write (first use of va/vb waits the loads)
#pragma unroll
        for (int r = 0; r < 4; ++r) {
            uint2 u; u.x = pk2(va[r].x, va[r].y); u.y = pk2(va[r].z, va[r].w);
            *(uint2*)(ldsAc + wA + r * 4096) = u;
        }
        {
            uint2 u;
            u.x = pk2(vb[0].x, vb[1].x); u.y = pk2(vb[2].x, vb[3].x);
            *(uint2*)(ldsBc + wB[0]) = u;
            u.x = pk2(vb[0].y, vb[1].y); u.y = pk2(vb[2].y, vb[3].y);
            *(uint2*)(ldsBc + wB[1]) = u;
            u.x = pk2(vb[0].z, vb[1].z); u.y = pk2(vb[2].z, vb[3].z);
            *(uint2*)(ldsBc + wB[2]) = u;
            u.x = pk2(vb[0].w, vb[1].w); u.y = pk2(vb[2].w, vb[3].w);
            *(uint2*)(ldsBc + wB[3]) = u;
        }
        __syncthreads();
        if (kk + 1 < KSTEPS) issue(kk + 1);       // in flight across MFMAs
#pragma unroll
        for (int h = 0; h < 2; ++h) {
            bf16x8 af[4], bfr[2];
#pragma unroll
            for (int a = 0; a < 4; ++a)
                af[a] = *(const bf16x8*)(ldsAc + ((baseA + a * 2048) ^ ((h ^ (a & 1)) << 6)));
#pragma unroll
            for (int b = 0; b < 2; ++b)
                bfr[b] = *(const bf16x8*)(ldsBc + ((baseB + b * 2048) ^ ((h ^ (b & 1)) << 6)));
#pragma unroll
            for (int a = 0; a < 4; ++a)
#pragma unroll
                for (int b = 0; b < 2; ++b)
                    acc[a][b] = __builtin_amdgcn_mfma_f32_16x16x32_bf16(af[a], bfr[b], acc[a][b], 0, 0, 0);
        }
        __syncthreads();
    }

    // epilogue: D layout col = fm, row = fq*4 + r
    float* outp = Mp + (size_t)ks * MSIZE;
    int gr0 = m0 + wr * 64, gc0 = n0 + wc * 32;
#pragma unroll
    for (int a = 0; a < 4; ++a)
#pragma unroll
        for (int r = 0; r < 4; ++r) {
            int row = gr0 + a * 16 + fq * 4 + r;
#pragma unroll
            for (int b = 0; b < 2; ++b)
                outp[(size_t)row * MCOLS + gc0 + b * 16 + fm] = acc[a][b][r];
        }
}

// ---------------------------------------------------------------------------
// k_pair: o[i,b] = sum_j exp(-L1(M_i,M_j)) -> out[:, 8192:8256], plus the
// x -> out[:, :8192] copy fused in (loads issued first, stores at the end,
// so the 32 MB copy hides under the VALU-bound pairwise loop).
// Split-K reduction fused into LDS staging (verbatim structure from R6).
// ---------------------------------------------------------------------------
__global__ __launch_bounds__(512, 2) void k_pair(const float* __restrict__ x,
                                                 const float* __restrict__ Mp,
                                                 float* __restrict__ out) {
    __shared__ float ldsM[NROWS * 20];                  // 40960 B, padded rows
    __shared__ float partial[8][64];
    int bid = blockIdx.x, t = threadIdx.x;
    int b = bid & 63, itp = bid >> 6;

    // copy prologue: rows bid*2 .. bid*2+2 of x (issue loads early)
    float4 cv[8];
    {
        const float* src = x + (size_t)bid * 2 * FEAT;
#pragma unroll
        for (int i = 0; i < 8; ++i) {
            int idx = t + i * 512;                      // row = idx>>11, col4 = idx&2047
            cv[i] = *(const float4*)(src + (size_t)(idx >> 11) * FEAT + (idx & 2047) * 4);
        }
    }

#pragma unroll
    for (int p = 0; p < 4; ++p) {
        int idx = t + p * 512;                // 2048 float4 total
        int j = idx >> 2, c4 = idx & 3;
        const float* base = Mp + (size_t)j * MCOLS + b * CDIM + c4 * 4;
        float4 s = *(const float4*)base;
#pragma unroll
        for (int k = 1; k < KSPLIT; ++k) {
            float4 v = *(const float4*)(base + (size_t)k * MSIZE);
            s.x += v.x; s.y += v.y; s.z += v.z; s.w += v.w;
        }
        *(float4*)&ldsM[j * 20 + c4 * 4] = s;
    }
    __syncthreads();

    int lane = t & 63, w = t >> 6, g = t >> 8, wg = (t >> 6) & 3;
    int i = (itp * 2 + g) * 64 + lane;
    float mi[CDIM];
#pragma unroll
    for (int cc = 0; cc < CDIM; ++cc) mi[cc] = ldsM[i * 20 + cc];

    float acc = 0.0f;
    for (int jj = wg * 128; jj < wg * 128 + 128; ++jj) {
        float d = 0.0f;
#pragma unroll
        for (int cc = 0; cc < CDIM; ++cc) d += fabsf(mi[cc] - ldsM[jj * 20 + cc]);
        acc += __expf(-d);
    }
    partial[w][lane] = acc;
    __syncthreads();
    if ((t & 255) < 64) {
        int ii = (itp * 2 + g) * 64 + (t & 63);
        float o = partial[g * 4 + 0][t & 63] + partial[g * 4 + 1][t & 63] +
                  partial[g * 4 + 2][t & 63] + partial[g * 4 + 3][t & 63];
        out[(size_t)ii * OUTC + FEAT + b] = o;
    }

    // copy epilogue: stores (cv held in regs across the compute phase)
    {
        float* dst = out + (size_t)bid * 2 * OUTC;
#pragma unroll
        for (int i2 = 0; i2 < 8; ++i2) {
            int idx = t + i2 * 512;
            *(float4*)(dst + (size_t)(idx >> 11) * OUTC + (idx & 2047) * 4) = cv[i2];
        }
    }
}

// ---------------------------------------------------------------------------
extern "C" void kernel_launch(void* const* d_in, const int* in_sizes, int n_in,
                              void* d_out, int out_size, void* d_ws, size_t ws_size,
                              hipStream_t stream) {
    const float* x = (const float*)d_in[0];      // (512, 8192)
    const float* T = (const float*)d_in[1];      // (8192, 1024)
    float* out = (float*)d_out;                  // (512, 8256)

    // ws layout: Mp 8 x 2MB = 16 MB at offset 0
    float* Mp = (float*)d_ws;

    k_gemm<<<256, 512, 0, stream>>>(x, T, Mp);
    k_pair<<<256, 512, 0, stream>>>(x, Mp, out);
}

// Round 2
// 130.306 us; speedup vs baseline: 1.1148x; 1.1148x over previous
//
#include <hip/hip_runtime.h>

// Problem constants
#define NROWS 512          // N
#define FEAT  8192         // NUM_CHANNELS*4*4
#define BDIM  64
#define CDIM  16
#define MCOLS 1024         // BDIM*CDIM
#define OUTC  8256         // FEAT + BDIM
#define KSPLIT 8
#define KCHUNK (FEAT / KSPLIT)     // 1024
#define KSTEPS (KCHUNK / 64)       // 16
#define MSIZE  (NROWS * MCOLS)     // 524288 floats = 2 MB

typedef __bf16 bf16x8 __attribute__((ext_vector_type(8)));
typedef float  floatx4 __attribute__((ext_vector_type(4)));

// two fp32 -> packed bf16 pair (HW RNE)
static __device__ __forceinline__ unsigned int pk2(float a, float b) {
    unsigned short lo = __builtin_bit_cast(unsigned short, (__bf16)a);
    unsigned short hi = __builtin_bit_cast(unsigned short, (__bf16)b);
    return (unsigned int)lo | ((unsigned int)hi << 16);
}

// ---------------------------------------------------------------------------
// k_gemm: M = x@T, fused fp32->bf16 + T-transpose in staging.
// 128x128 tile, 512 thr (8 waves 2x4), BK=64, split-K=8, grid 256 = 1 blk/CU.
// Double-buffered LDS (2x32KB), ONE raw s_barrier per K-step with explicit
// s_waitcnt lgkmcnt(0) only -- global prefetch loads (distance 2) stay in
// flight across barriers (never vmcnt(0) in the loop; that was the R1 stall:
// __syncthreads drains vmcnt, exposing a full L2 round trip per step).
// Single-barrier safety: write(k) races only MFMA(k-2) reads of the same
// buffer; those finished before barrier(k-1) because every wave executes
// lgkmcnt(0) (covers its ds_reads) before each barrier.
// ---------------------------------------------------------------------------
__global__ __launch_bounds__(512, 2) void k_gemm(const float* __restrict__ x,
                                                 const float* __restrict__ T,
                                                 float* __restrict__ Mp) {
    __shared__ __align__(16) unsigned short ldsA[2][128 * 64];   // 32 KB
    __shared__ __align__(16) unsigned short ldsB[2][128 * 64];   // 32 KB
    char* ldsAc = (char*)ldsA;
    char* ldsBc = (char*)ldsB;

    int bid = blockIdx.x;
    int wg = (bid & 7) * 32 + (bid >> 3);        // XCD-contiguous remap
    int mt = wg & 3, nt = (wg >> 2) & 7, ks = wg >> 5;
    int m0 = mt * 128, n0 = nt * 128, kbase = ks * KCHUNK;
    int t = threadIdx.x, w = t >> 6, l = t & 63;

    // ---- staging geometry: A rows (k-contiguous, no transpose)
    int arow = t >> 4, aq = t & 15;              // 32 rows (+r*32), 16 k-quads
    const float* gA = x + (size_t)(m0 + arow) * FEAT + kbase + aq * 4;
    int swa = (arow & 7) ^ ((arow >> 2) & 7);    // invariant under +32 rows
    int wA = arow * 128 + (((aq >> 1) ^ swa) << 4) + ((aq & 1) << 3);

    // ---- staging geometry: B (transpose T[k][n] -> n-major rows)
    int n4 = t & 31, kg = t >> 5;                // 32 n-quads, 16 k-quads
    const float* gB = T + (size_t)(kbase + kg * 4) * MCOLS + n0 + n4 * 4;
    int wB[4];
#pragma unroll
    for (int j = 0; j < 4; ++j) {
        int n = n4 * 4 + j;
        int swn = (n & 7) ^ ((n >> 2) & 7);
        wB[j] = n * 128 + (((kg >> 1) ^ swn) << 4) + ((kg & 1) << 3);
    }

    // ---- compute geometry: wave (wr=w>>2, wc=w&3) owns 64x32 of C
    int wr = w >> 2, wc = w & 3, fm = l & 15, fq = l >> 4;
    int swf = (fm & 7) ^ ((fm >> 2) & 7);
    int baseA = (wr * 64 + fm) * 128 + ((fq ^ swf) << 4);
    int baseB = (wc * 32 + fm) * 128 + ((fq ^ swf) << 4);

    floatx4 acc[4][2] = {};
    float4 va0[4], vb0[4], va1[4], vb1[4];

    auto issue = [&](int KK, float4* A4, float4* B4) {
        const float* pa = gA + KK * 64;
        A4[0] = *(const float4*)(pa);
        A4[1] = *(const float4*)(pa + 32 * FEAT);
        A4[2] = *(const float4*)(pa + 64 * FEAT);
        A4[3] = *(const float4*)(pa + 96 * FEAT);
        const float* pb = gB + (size_t)KK * 64 * MCOLS;
        B4[0] = *(const float4*)(pb);
        B4[1] = *(const float4*)(pb + MCOLS);
        B4[2] = *(const float4*)(pb + 2 * MCOLS);
        B4[3] = *(const float4*)(pb + 3 * MCOLS);
    };

    auto step = [&](int KK, int SO, float4* A4, float4* B4) {
        // cvt + LDS write into buffer SO (waits vmcnt for this set only)
#pragma unroll
        for (int r = 0; r < 4; ++r) {
            uint2 u; u.x = pk2(A4[r].x, A4[r].y); u.y = pk2(A4[r].z, A4[r].w);
            *(uint2*)(ldsAc + SO + wA + r * 4096) = u;
        }
        {
            uint2 u;
            u.x = pk2(B4[0].x, B4[1].x); u.y = pk2(B4[2].x, B4[3].x);
            *(uint2*)(ldsBc + SO + wB[0]) = u;
            u.x = pk2(B4[0].y, B4[1].y); u.y = pk2(B4[2].y, B4[3].y);
            *(uint2*)(ldsBc + SO + wB[1]) = u;
            u.x = pk2(B4[0].z, B4[1].z); u.y = pk2(B4[2].z, B4[3].z);
            *(uint2*)(ldsBc + SO + wB[2]) = u;
            u.x = pk2(B4[0].w, B4[1].w); u.y = pk2(B4[2].w, B4[3].w);
            *(uint2*)(ldsBc + SO + wB[3]) = u;
        }
        // prefetch distance 2 into the register set we just drained;
        // issued BEFORE the barrier so the loads fly during barrier wait.
        if (KK + 2 < KSTEPS) issue(KK + 2, A4, B4);
        asm volatile("s_waitcnt lgkmcnt(0)" ::: "memory");   // LDS only; vmcnt stays
        __builtin_amdgcn_s_barrier();
        // MFMA phase reading buffer SO
#pragma unroll
        for (int h = 0; h < 2; ++h) {
            bf16x8 af[4], bfr[2];
#pragma unroll
            for (int a = 0; a < 4; ++a)
                af[a] = *(const bf16x8*)(ldsAc + SO + ((baseA + a * 2048) ^ ((h ^ (a & 1)) << 6)));
#pragma unroll
            for (int b = 0; b < 2; ++b)
                bfr[b] = *(const bf16x8*)(ldsBc + SO + ((baseB + b * 2048) ^ ((h ^ (b & 1)) << 6)));
#pragma unroll
            for (int a = 0; a < 4; ++a)
#pragma unroll
                for (int b = 0; b < 2; ++b)
                    acc[a][b] = __builtin_amdgcn_mfma_f32_16x16x32_bf16(af[a], bfr[b], acc[a][b], 0, 0, 0);
        }
    };

    issue(0, va0, vb0);
    issue(1, va1, vb1);
    for (int kk = 0; kk < KSTEPS; kk += 2) {
        step(kk,     0,     va0, vb0);
        step(kk + 1, 16384, va1, vb1);
    }

    // epilogue: D layout col = fm, row = fq*4 + r
    float* outp = Mp + (size_t)ks * MSIZE;
    int gr0 = m0 + wr * 64, gc0 = n0 + wc * 32;
#pragma unroll
    for (int a = 0; a < 4; ++a)
#pragma unroll
        for (int r = 0; r < 4; ++r) {
            int row = gr0 + a * 16 + fq * 4 + r;
#pragma unroll
            for (int b = 0; b < 2; ++b)
                outp[(size_t)row * MCOLS + gc0 + b * 16 + fm] = acc[a][b][r];
        }
}

// ---------------------------------------------------------------------------
// k_pair: o[i,b] = sum_j exp(-L1(M_i,M_j)) -> out[:, 8192:8256], plus the
// x -> out[:, :8192] copy STREAMED (load->store immediately; R1's reg-held
// copy spilled -- VGPR_Count 44 cannot hold 8 float4). Mp staging loads are
// issued first (critical path), copy pipelines behind them on vmcnt.
// ---------------------------------------------------------------------------
__global__ __launch_bounds__(512, 2) void k_pair(const float* __restrict__ x,
                                                 const float* __restrict__ Mp,
                                                 float* __restrict__ out) {
    __shared__ float ldsM[NROWS * 20];                  // 40960 B, padded rows
    __shared__ float partial[8][64];
    int bid = blockIdx.x, t = threadIdx.x;
    int b = bid & 63, itp = bid >> 6;

#pragma unroll
    for (int p = 0; p < 4; ++p) {
        int idx = t + p * 512;                // 2048 float4 total
        int j = idx >> 2, c4 = idx & 3;
        const float* base = Mp + (size_t)j * MCOLS + b * CDIM + c4 * 4;
        float4 s = *(const float4*)base;
#pragma unroll
        for (int k = 1; k < KSPLIT; ++k) {
            float4 v = *(const float4*)(base + (size_t)k * MSIZE);
            s.x += v.x; s.y += v.y; s.z += v.z; s.w += v.w;
        }
        *(float4*)&ldsM[j * 20 + c4 * 4] = s;
    }

    // streaming copy: rows bid*2 .. bid*2+1 of x -> out[:, :8192]
    {
        const float* src = x + (size_t)bid * 2 * FEAT;
        float* dst = out + (size_t)bid * 2 * OUTC;
#pragma unroll
        for (int i = 0; i < 8; ++i) {
            int idx = t + i * 512;            // row = idx>>11, col4 = idx&2047
            float4 v = *(const float4*)(src + (size_t)(idx >> 11) * FEAT + (idx & 2047) * 4);
            *(float4*)(dst + (size_t)(idx >> 11) * OUTC + (idx & 2047) * 4) = v;
        }
    }
    __syncthreads();

    int lane = t & 63, w = t >> 6, g = t >> 8, wg = (t >> 6) & 3;
    int i = (itp * 2 + g) * 64 + lane;
    float mi[CDIM];
#pragma unroll
    for (int cc = 0; cc < CDIM; ++cc) mi[cc] = ldsM[i * 20 + cc];

    float acc = 0.0f;
    for (int jj = wg * 128; jj < wg * 128 + 128; ++jj) {
        float d = 0.0f;
#pragma unroll
        for (int cc = 0; cc < CDIM; ++cc) d += fabsf(mi[cc] - ldsM[jj * 20 + cc]);
        acc += __expf(-d);
    }
    partial[w][lane] = acc;
    __syncthreads();
    if ((t & 255) < 64) {
        int ii = (itp * 2 + g) * 64 + (t & 63);
        float o = partial[g * 4 + 0][t & 63] + partial[g * 4 + 1][t & 63] +
                  partial[g * 4 + 2][t & 63] + partial[g * 4 + 3][t & 63];
        out[(size_t)ii * OUTC + FEAT + b] = o;
    }
}

// ---------------------------------------------------------------------------
extern "C" void kernel_launch(void* const* d_in, const int* in_sizes, int n_in,
                              void* d_out, int out_size, void* d_ws, size_t ws_size,
                              hipStream_t stream) {
    const float* x = (const float*)d_in[0];      // (512, 8192)
    const float* T = (const float*)d_in[1];      // (8192, 1024)
    float* out = (float*)d_out;                  // (512, 8256)

    // ws layout: Mp 8 x 2MB = 16 MB at offset 0
    float* Mp = (float*)d_ws;

    k_gemm<<<256, 512, 0, stream>>>(x, T, Mp);
    k_pair<<<256, 512, 0, stream>>>(x, Mp, out);
}